// Round 4
// baseline (15337.668 us; speedup 1.0000x reference)
//
#include <hip/hip_runtime.h>
#include <math.h>

// DualEncoder: two LSTMs (B=64,T=160,E=512,H=1024) + bilinear sigmoid.
// mode 2: cvt to bf16 -> pre_gemm2 (X = emb@Wih^T + bias, all t) ->
//         ONE persistent kernel for all 160 recurrent steps (Whh in LDS,
//         c in registers, grid barrier between steps) -> bilinear.
// mode 1/0: round-3 fallback paths (smaller workspace).

#define BB 64
#define TT 160
#define EE 512
#define HH 1024
#define G4 4096
#define ROWS 128
#define NB 256          // persistent grid size

typedef unsigned short u16;
typedef unsigned int u32;
typedef __attribute__((ext_vector_type(8))) __bf16 bf16x8;
typedef __attribute__((ext_vector_type(8))) short short8;
typedef __attribute__((ext_vector_type(4))) short short4v;
typedef __attribute__((ext_vector_type(4))) float f32x4;

__device__ __forceinline__ u16 f2b(float f) {          // f32 -> bf16 RNE
    unsigned u = __float_as_uint(f);
    u = u + 0x7fffu + ((u >> 16) & 1u);
    return (u16)(u >> 16);
}
__device__ __forceinline__ float b2f(u16 s) { return __uint_as_float(((unsigned)s) << 16); }

__device__ __forceinline__ f32x4 mfma16(short8 a, short8 b, f32x4 c) {
    return __builtin_amdgcn_mfma_f32_16x16x32_bf16(
        __builtin_bit_cast(bf16x8, a), __builtin_bit_cast(bf16x8, b), c, 0, 0, 0);
}

__device__ __forceinline__ void g2l16(const void* gsrc, void* ldst) {
    __builtin_amdgcn_global_load_lds(
        (const __attribute__((address_space(1))) u32*)gsrc,
        (__attribute__((address_space(3))) u32*)ldst, 16, 0, 0);
}

// ---------------- f32 -> bf16 bulk convert ----------------
__global__ __launch_bounds__(256) void cvt_kernel(const float* __restrict__ in,
                                                  u16* __restrict__ out, int n4) {
    int i = blockIdx.x * 256 + threadIdx.x;
    if (i < n4) {
        f32x4 v = *(const f32x4*)(in + (size_t)i * 4);
        short4v o;
        o.x = (short)f2b(v.x); o.y = (short)f2b(v.y);
        o.z = (short)f2b(v.z); o.w = (short)f2b(v.w);
        *(short4v*)(out + (size_t)i * 4) = o;
    }
}

// ---------------- X precompute (unchanged from round 3, verified) ----------
__global__ __launch_bounds__(256) void pre_gemm2(
    const int* __restrict__ ctx, const int* __restrict__ rsp,
    const u16* __restrict__ embb, const u16* __restrict__ Wihb,
    const float* __restrict__ bih, const float* __restrict__ bhh,
    u16* __restrict__ xg)
{
    __shared__ __align__(16) u16 As[2][128][64];
    __shared__ __align__(16) u16 Ws[2][128][64];
    __shared__ int toks[128];
    const int tid = threadIdx.x;
    const int n0 = blockIdx.x * 128;
    const int t  = blockIdx.y;

    if (tid < 128) {
        int r = tid;
        toks[tid] = (r < BB) ? ctx[r * TT + t] : rsp[(r - BB) * TT + t];
    }
    __syncthreads();

    const u16* asrc[4]; const u16* bsrc[4];
    #pragma unroll
    for (int q = 0; q < 4; ++q) {
        int i = tid + q * 256;
        int row = i >> 3, c16 = i & 7;
        int scol = ((c16 ^ (row & 7)) * 8);
        asrc[q] = embb + (size_t)toks[row] * EE + scol;
        bsrc[q] = Wihb + (size_t)(n0 + row) * EE + scol;
    }

    const int lane = tid & 63, wave = tid >> 6;
    const int wr = (wave >> 1) * 64, wc = (wave & 1) * 64;
    const int l15 = lane & 15, l4 = lane >> 4;
    f32x4 acc[4][4] = {};

    #pragma unroll
    for (int q = 0; q < 4; ++q) {
        g2l16(asrc[q], (char*)&As[0][0][0] + (tid + q * 256) * 16);
        g2l16(bsrc[q], (char*)&Ws[0][0][0] + (tid + q * 256) * 16);
    }
    for (int it = 0; it < 8; ++it) {
        __syncthreads();
        if (it + 1 < 8) {
            int kk = (it + 1) * 64, bs = (it + 1) & 1;
            #pragma unroll
            for (int q = 0; q < 4; ++q) {
                g2l16(asrc[q] + kk, (char*)&As[bs][0][0] + (tid + q * 256) * 16);
                g2l16(bsrc[q] + kk, (char*)&Ws[bs][0][0] + (tid + q * 256) * 16);
            }
        }
        const int b = it & 1;
        #pragma unroll
        for (int ks = 0; ks < 2; ++ks) {
            int c16 = ks * 4 + l4;
            short8 a[4], w[4];
            #pragma unroll
            for (int mf = 0; mf < 4; ++mf) {
                int R = wr + mf * 16 + l15;
                a[mf] = *(const short8*)((const char*)&As[b][0][0] + R * 128 + ((c16 ^ (R & 7)) << 4));
            }
            #pragma unroll
            for (int nf = 0; nf < 4; ++nf) {
                int Nn = wc + nf * 16 + l15;
                w[nf] = *(const short8*)((const char*)&Ws[b][0][0] + Nn * 128 + ((c16 ^ (Nn & 7)) << 4));
            }
            #pragma unroll
            for (int mf = 0; mf < 4; ++mf)
                #pragma unroll
                for (int nf = 0; nf < 4; ++nf)
                    acc[mf][nf] = mfma16(a[mf], w[nf], acc[mf][nf]);
        }
    }

    u16* xp = xg + (size_t)t * ROWS * G4;
    #pragma unroll
    for (int nf = 0; nf < 4; ++nf) {
        int n = n0 + wc + nf * 16 + l15;
        float bias = bih[n] + bhh[n];
        #pragma unroll
        for (int mf = 0; mf < 4; ++mf)
            #pragma unroll
            for (int q = 0; q < 4; ++q) {
                int r = wr + mf * 16 + l4 * 4 + q;
                xp[(size_t)r * G4 + n] = f2b(acc[mf][nf][q] + bias);
            }
    }
}

// ---------------- persistent recurrent kernel ----------------
// 256 blocks x 512 threads. Block bx: cg = bx&127 (h-cols j0=cg*8, gate-cols
// n = g*1024+j0+jj), rg = bx>>7 (rows r0=rg*64). Whh slice (32 rows x 1024 K,
// 64 KB) stays in LDS for all 160 steps. 8 waves = rsub(2) x kh(4); wave tile
// 32 rows x 32 cols x K=256. Partials combined in LDS (two rounds, no
// atomics). c in registers (1 cell/thread). One grid barrier per step.
__global__ __launch_bounds__(512) void lstm_persist(
    const u16* __restrict__ Whhb, const u16* __restrict__ xg,
    u16* __restrict__ hbuf, unsigned* __restrict__ bar)
{
    __shared__ __align__(16) u16 Ws[32][1024];       // 64 KB, swizzled
    __shared__ float G[2][2][32][33];                // 16.9 KB partial buf

    const int tid = threadIdx.x;
    const int bx = blockIdx.x;
    const int cg = bx & 127, rg = bx >> 7;
    const int r0 = rg * 64, j0 = cg * 8;

    // ---- load Whh slice into LDS (once), XOR-swizzled 16B chunks ----
    {
        int cc = tid >> 4;                 // 0..31 local gate-row
        int c16b = (tid & 15) * 8;         // 16B-chunk base (of 128)
        int n = (cc >> 3) * HH + j0 + (cc & 7);
        const u16* src = Whhb + (size_t)n * HH;
        #pragma unroll
        for (int q = 0; q < 8; ++q) {
            int c16 = c16b + q;
            short8 v = *(const short8*)(src + c16 * 8);
            *(short8*)((char*)&Ws[0][0] + cc * 2048 + ((c16 ^ (cc & 7)) << 4)) = v;
        }
    }

    float c_reg = 0.f;                     // this thread's cell state
    const int rloc = tid >> 3;             // 0..63 (cell row)
    const int jj = tid & 7;                // h-col within block

    const int lane = tid & 63, wave = tid >> 6;
    const int rsub = wave >> 2;            // 0/1 (row half)
    const int kh   = wave & 3;             // 0..3 (K quarter)
    const int l15 = lane & 15, l4 = lane >> 4;

    __syncthreads();

    for (int t = 0; t < TT; ++t) {
        const u16* hin = hbuf + (size_t)(t & 1) * ROWS * HH;
        u16* hout      = hbuf + (size_t)((t + 1) & 1) * ROWS * HH;

        // ---- GEMM: 32x32 wave tile, K = kh*256 .. +256 ----
        f32x4 acc[2][2] = {};
        const u16* abase = hin + (size_t)(r0 + rsub * 32 + l15) * HH + kh * 256 + l4 * 8;
        #pragma unroll
        for (int ks = 0; ks < 8; ++ks) {
            short8 a0 = *(const short8*)(abase + ks * 32);
            short8 a1 = *(const short8*)(abase + 16 * HH + ks * 32);
            int c16 = kh * 32 + ks * 4 + l4;
            int rb0 = l15, rb1 = 16 + l15;
            short8 b0 = *(const short8*)((const char*)&Ws[0][0] + rb0 * 2048 + ((c16 ^ (rb0 & 7)) << 4));
            short8 b1 = *(const short8*)((const char*)&Ws[0][0] + rb1 * 2048 + ((c16 ^ (rb1 & 7)) << 4));
            acc[0][0] = mfma16(a0, b0, acc[0][0]);
            acc[0][1] = mfma16(a0, b1, acc[0][1]);
            acc[1][0] = mfma16(a1, b0, acc[1][0]);
            acc[1][1] = mfma16(a1, b1, acc[1][1]);
        }

        // ---- combine K-partials: waves kh<2 store, kh>=2 add ----
        if (kh < 2) {
            #pragma unroll
            for (int mf = 0; mf < 2; ++mf)
                #pragma unroll
                for (int nf = 0; nf < 2; ++nf)
                    #pragma unroll
                    for (int q = 0; q < 4; ++q)
                        G[kh][rsub][mf * 16 + l4 * 4 + q][nf * 16 + l15] = acc[mf][nf][q];
        }
        __syncthreads();
        if (kh >= 2) {
            #pragma unroll
            for (int mf = 0; mf < 2; ++mf)
                #pragma unroll
                for (int nf = 0; nf < 2; ++nf)
                    #pragma unroll
                    for (int q = 0; q < 4; ++q)
                        G[kh - 2][rsub][mf * 16 + l4 * 4 + q][nf * 16 + l15] += acc[mf][nf][q];
        }
        __syncthreads();

        // ---- cell update (1 cell per thread) ----
        {
            const int rs = rloc >> 5, rl = rloc & 31;
            const u16* xp = xg + ((size_t)t * ROWS + (r0 + rloc)) * G4 + j0 + jj;
            float g[4];
            #pragma unroll
            for (int q = 0; q < 4; ++q)
                g[q] = G[0][rs][rl][q * 8 + jj] + G[1][rs][rl][q * 8 + jj] + b2f(xp[(size_t)q * HH]);
            float ii = 1.f / (1.f + expf(-g[0]));
            float ff = 1.f / (1.f + expf(-g[1]));
            float gg = tanhf(g[2]);
            float oo = 1.f / (1.f + expf(-g[3]));
            c_reg = ff * c_reg + ii * gg;
            hout[(size_t)(r0 + rloc) * HH + j0 + jj] = f2b(oo * tanhf(c_reg));
        }

        // ---- grid barrier (skip after last step; kernel end releases) ----
        if (t < TT - 1) {
            __threadfence();               // release h writes (all threads)
            __syncthreads();
            if (tid == 0) {
                atomicAdd(bar, 1u);
                unsigned target = (unsigned)(t + 1) * (unsigned)NB;
                long spins = 0;
                while (__hip_atomic_load(bar, __ATOMIC_RELAXED, __HIP_MEMORY_SCOPE_AGENT) < target) {
                    __builtin_amdgcn_s_sleep(2);
                    if (++spins > 400000000L) break;   // safety bailout
                }
            }
            __syncthreads();
            __threadfence();               // acquire: invalidate stale caches
        }
    }
}

// ---------------- round-3 fallback: fused per-step kernel ----------------
template<int MODE>
__global__ __launch_bounds__(256) void step_fused(
    const int* __restrict__ ctx, const int* __restrict__ rsp,
    const u16* __restrict__ embb, const u16* __restrict__ Wihb,
    const u16* __restrict__ Whhb, const u16* __restrict__ xg,
    const float* __restrict__ bih, const float* __restrict__ bhh,
    const u16* __restrict__ hin, u16* __restrict__ hout,
    float* __restrict__ c_ws, int t)
{
    __shared__ __align__(16) u16 As[2][64][64];
    __shared__ __align__(16) u16 Ws[2][32][64];
    __shared__ float gs[64][32];
    __shared__ int toks[64];

    const int tid = threadIdx.x;
    const int cg = blockIdx.x & 127, rg = blockIdx.x >> 7;
    const int r0 = rg * 64, j0 = cg * 8;

    if (MODE == 1) {
        if (tid < 64) {
            int r = r0 + tid;
            toks[tid] = (r < BB) ? ctx[r * TT + t] : rsp[(r - BB) * TT + t];
        }
        __syncthreads();
    }

    const int arow0 = tid >> 3, c16a = tid & 7;
    const int arow1 = arow0 + 32;
    const int acol0 = ((c16a ^ (arow0 & 7)) * 8);
    const int acol1 = ((c16a ^ (arow1 & 7)) * 8);
    const u16* hA0 = hin + (size_t)(r0 + arow0) * HH + acol0;
    const u16* hA1 = hin + (size_t)(r0 + arow1) * HH + acol1;
    const u16* eA0 = nullptr; const u16* eA1 = nullptr;
    if (MODE == 1) {
        eA0 = embb + (size_t)toks[arow0] * EE + acol0;
        eA1 = embb + (size_t)toks[arow1] * EE + acol1;
    }
    const int nn = tid >> 3, c16b = tid & 7;
    const int bcol = ((c16b ^ (nn & 7)) * 8);
    const int wrow = (nn >> 3) * HH + j0 + (nn & 7);
    const u16* wHh = Whhb + (size_t)wrow * HH + bcol;
    const u16* wIh = (MODE == 1) ? (Wihb + (size_t)wrow * EE + bcol) : nullptr;

    const int NK = (MODE == 1) ? 24 : 16;

    auto stage = [&](int bs, int it) {
        int kk = it * 64;
        const u16 *s0, *s1, *sw;
        if (MODE == 1 && kk < EE) {
            s0 = eA0 + kk; s1 = eA1 + kk; sw = wIh + kk;
        } else {
            int khh = (MODE == 1) ? kk - EE : kk;
            s0 = hA0 + khh; s1 = hA1 + khh; sw = wHh + khh;
        }
        g2l16(s0, (char*)&As[bs][0][0] + tid * 16);
        g2l16(s1, (char*)&As[bs][0][0] + (tid + 256) * 16);
        g2l16(sw, (char*)&Ws[bs][0][0] + tid * 16);
    };

    const int lane = tid & 63, wave = tid >> 6;
    const int wr = wave * 16;
    const int l15 = lane & 15, l4 = lane >> 4;
    f32x4 acc[2] = {};

    stage(0, 0);
    for (int it = 0; it < NK; ++it) {
        __syncthreads();
        if (it + 1 < NK) stage((it + 1) & 1, it + 1);
        const int b = it & 1;
        #pragma unroll
        for (int ks = 0; ks < 2; ++ks) {
            int c16 = ks * 4 + l4;
            int R = wr + l15;
            short8 a = *(const short8*)((const char*)&As[b][0][0] + R * 128 + ((c16 ^ (R & 7)) << 4));
            #pragma unroll
            for (int nf = 0; nf < 2; ++nf) {
                int Nn = nf * 16 + l15;
                short8 w = *(const short8*)((const char*)&Ws[b][0][0] + Nn * 128 + ((c16 ^ (Nn & 7)) << 4));
                acc[nf] = mfma16(a, w, acc[nf]);
            }
        }
    }
    __syncthreads();
    #pragma unroll
    for (int nf = 0; nf < 2; ++nf)
        #pragma unroll
        for (int q = 0; q < 4; ++q)
            gs[wr + l4 * 4 + q][nf * 16 + l15] = acc[nf][q];
    __syncthreads();

    const int e = tid * 2;
    const int row = e >> 3, jj = e & 7;
    const int rglob = r0 + row;
    float g0[4], g1[4];
    #pragma unroll
    for (int g = 0; g < 4; ++g) { g0[g] = gs[row][g * 8 + jj]; g1[g] = gs[row][g * 8 + jj + 1]; }
    if (MODE == 2) {
        const u16* xp = xg + ((size_t)t * ROWS + rglob) * G4 + j0 + jj;
        #pragma unroll
        for (int g = 0; g < 4; ++g) { g0[g] += b2f(xp[g * HH]); g1[g] += b2f(xp[g * HH + 1]); }
    } else {
        #pragma unroll
        for (int g = 0; g < 4; ++g) {
            int n = g * HH + j0 + jj;
            g0[g] += bih[n] + bhh[n];
            g1[g] += bih[n + 1] + bhh[n + 1];
        }
    }
    size_t cidx = ((size_t)blockIdx.x * 64 + row) * 8 + jj;
    float c0 = c_ws[cidx], c1 = c_ws[cidx + 1];
    float i0 = 1.f / (1.f + expf(-g0[0])), i1 = 1.f / (1.f + expf(-g1[0]));
    float f0 = 1.f / (1.f + expf(-g0[1])), f1 = 1.f / (1.f + expf(-g1[1]));
    float t0 = tanhf(g0[2]),               t1 = tanhf(g1[2]);
    float o0 = 1.f / (1.f + expf(-g0[3])), o1 = 1.f / (1.f + expf(-g1[3]));
    float cn0 = f0 * c0 + i0 * t0;
    float cn1 = f1 * c1 + i1 * t1;
    c_ws[cidx] = cn0; c_ws[cidx + 1] = cn1;
    float h0 = o0 * tanhf(cn0), h1 = o1 * tanhf(cn1);
    unsigned hp = (unsigned)f2b(h0) | ((unsigned)f2b(h1) << 16);
    *(unsigned*)(hout + (size_t)rglob * HH + j0 + jj) = hp;
}

// ---------------- mode-0 fallback ----------------
__global__ __launch_bounds__(256) void step_gemm_f32(
    const int* __restrict__ ctx, const int* __restrict__ rsp,
    const float* __restrict__ emb, const float* __restrict__ Wih, const float* __restrict__ Whh,
    const u16* __restrict__ hb, float* __restrict__ gates, int t)
{
    __shared__ __align__(16) u16 As[64][32];
    __shared__ __align__(16) u16 Ws[64][32];
    __shared__ int toks[64];
    const int tid = threadIdx.x;
    const int n0 = blockIdx.x * 64;
    const int r0 = blockIdx.y * 64;
    const int part = blockIdx.z;
    if (tid < 64) {
        int r = r0 + tid;
        toks[tid] = (r < BB) ? ctx[r * TT + t] : rsp[(r - BB) * TT + t];
    }
    __syncthreads();
    const int lane = tid & 63, wave = tid >> 6;
    const int wr = (wave >> 1) * 32, wc = (wave & 1) * 32;
    const int l15 = lane & 15, l4 = lane >> 4;
    f32x4 acc[2][2] = {};
    const int kstart = part * 768;
    const int srow = tid >> 2;
    const int sseg = (tid & 3) * 8;
    for (int it = 0; it < 24; ++it) {
        const int kg = kstart + it * 32;
        const int kk = kg + sseg;
        if (kg < EE) {
            const float* s = emb + (size_t)toks[srow] * EE + kk;
            #pragma unroll
            for (int q = 0; q < 8; ++q) As[srow][sseg + q] = f2b(s[q]);
            const float* sw = Wih + (size_t)(n0 + srow) * EE + kk;
            #pragma unroll
            for (int q = 0; q < 8; ++q) Ws[srow][sseg + q] = f2b(sw[q]);
        } else {
            *(short8*)&As[srow][sseg] = *(const short8*)(hb + (size_t)(r0 + srow) * HH + (kk - EE));
            const float* sw = Whh + (size_t)(n0 + srow) * HH + (kk - EE);
            #pragma unroll
            for (int q = 0; q < 8; ++q) Ws[srow][sseg + q] = f2b(sw[q]);
        }
        __syncthreads();
        #pragma unroll
        for (int mf = 0; mf < 2; ++mf)
            #pragma unroll
            for (int nf = 0; nf < 2; ++nf)
                acc[mf][nf] = mfma16(*(const short8*)&As[wr + mf * 16 + l15][l4 * 8],
                                     *(const short8*)&Ws[wc + nf * 16 + l15][l4 * 8], acc[mf][nf]);
        __syncthreads();
    }
    float* gp = gates + (size_t)part * ROWS * G4;
    #pragma unroll
    for (int mf = 0; mf < 2; ++mf)
        #pragma unroll
        for (int nf = 0; nf < 2; ++nf)
            #pragma unroll
            for (int q = 0; q < 4; ++q) {
                int r = r0 + wr + mf * 16 + l4 * 4 + q;
                int n = n0 + wc + nf * 16 + l15;
                gp[(size_t)r * G4 + n] = acc[mf][nf][q];
            }
}

__global__ __launch_bounds__(256) void lstm_update0(
    const float* __restrict__ gates, const float* __restrict__ bih, const float* __restrict__ bhh,
    u16* __restrict__ hb, float* __restrict__ c)
{
    int idx = blockIdx.x * 256 + threadIdx.x;
    int r = idx >> 8;
    int jj = (idx & 255) * 4;
    const float* gp0 = gates + (size_t)r * G4;
    const float* gp1 = gates + (size_t)(ROWS + r) * G4;
    float gate[4][4];
    #pragma unroll
    for (int g = 0; g < 4; ++g) {
        int n = g * HH + jj;
        f32x4 a = *(const f32x4*)(gp0 + n);
        f32x4 b = *(const f32x4*)(gp1 + n);
        #pragma unroll
        for (int q = 0; q < 4; ++q) gate[g][q] = a[q] + b[q] + bih[n + q] + bhh[n + q];
    }
    int cidx = r * HH + jj;
    f32x4 cv = *(const f32x4*)(c + cidx);
    f32x4 cn; short4v hn;
    #pragma unroll
    for (int q = 0; q < 4; ++q) {
        float si = 1.f / (1.f + expf(-gate[0][q]));
        float sf = 1.f / (1.f + expf(-gate[1][q]));
        float tg = tanhf(gate[2][q]);
        float so = 1.f / (1.f + expf(-gate[3][q]));
        float cval = sf * cv[q] + si * tg;
        cn[q] = cval;
        ((short*)&hn)[q] = (short)f2b(so * tanhf(cval));
    }
    *(f32x4*)(c + cidx) = cn;
    *(short4v*)(hb + cidx) = hn;
}

// ---------------- bilinear head ----------------
__global__ __launch_bounds__(256) void bilinear(
    const u16* __restrict__ hb, const float* __restrict__ M, float* __restrict__ out)
{
    int b = blockIdx.x;
    __shared__ float chs[HH];
    __shared__ float red[256];
    const u16* ch = hb + (size_t)b * HH;
    const u16* rh = hb + (size_t)(BB + b) * HH;
    for (int i = threadIdx.x; i < HH; i += 256) chs[i] = b2f(ch[i]);
    __syncthreads();
    float vj[4] = {0.f, 0.f, 0.f, 0.f};
    for (int i = 0; i < HH; ++i) {
        float chi = chs[i];
        const float* Mr = M + (size_t)i * HH;
        #pragma unroll
        for (int q = 0; q < 4; ++q) vj[q] += chi * Mr[threadIdx.x + q * 256];
    }
    float acc = 0.f;
    #pragma unroll
    for (int q = 0; q < 4; ++q) acc += vj[q] * b2f(rh[threadIdx.x + q * 256]);
    red[threadIdx.x] = acc;
    __syncthreads();
    for (int s = 128; s > 0; s >>= 1) {
        if (threadIdx.x < s) red[threadIdx.x] += red[threadIdx.x + s];
        __syncthreads();
    }
    if (threadIdx.x == 0) out[b] = 1.0f / (1.0f + expf(-red[0]));
}

extern "C" void kernel_launch(void* const* d_in, const int* in_sizes, int n_in,
                              void* d_out, int out_size, void* d_ws, size_t ws_size,
                              hipStream_t stream) {
    const int*   ctx = (const int*)d_in[0];
    const int*   rsp = (const int*)d_in[1];
    const float* emb = (const float*)d_in[2];
    const float* Wih = (const float*)d_in[3];
    const float* Whh = (const float*)d_in[4];
    const float* bih = (const float*)d_in[5];
    const float* bhh = (const float*)d_in[6];
    const float* M   = (const float*)d_in[7];
    float* out = (float*)d_out;

    // workspace layout
    char* w = (char*)d_ws;
    u16*   hbuf  = (u16*)w;   w += (size_t)2 * ROWS * HH * 2;      // 512 KB
    float* c_ws  = (float*)w; w += (size_t)ROWS * HH * 4;          // 512 KB
    float* gates = (float*)w; w += (size_t)2 * ROWS * G4 * 4;      // 4 MB (mode 0)
    u16*   embb  = (u16*)w;   w += (size_t)32000 * EE * 2;         // 31.25 MB
    u16*   Wihb  = (u16*)w;   w += (size_t)G4 * EE * 2;            // 4 MB
    u16*   Whhb  = (u16*)w;   w += (size_t)G4 * HH * 2;            // 8 MB
    unsigned* bar = (unsigned*)w; w += 256;                        // barrier
    size_t conv_need = (size_t)(w - (char*)d_ws);
    u16*   xg    = (u16*)w;   w += (size_t)TT * ROWS * G4 * 2;     // 160 MB
    size_t xpre_need = (size_t)(w - (char*)d_ws);

    int mode = (ws_size >= xpre_need) ? 2 : (ws_size >= conv_need) ? 1 : 0;

    hipMemsetAsync(hbuf, 0, (size_t)2 * ROWS * HH * 2, stream);

    if (mode >= 1) {
        cvt_kernel<<<16000, 256, 0, stream>>>(emb, embb, 32000 * EE / 4);
        cvt_kernel<<<2048,  256, 0, stream>>>(Wih, Wihb, G4 * EE / 4);
        cvt_kernel<<<4096,  256, 0, stream>>>(Whh, Whhb, G4 * HH / 4);
    }

    if (mode == 2) {
        hipMemsetAsync(bar, 0, 256, stream);
        pre_gemm2<<<dim3(G4 / 128, TT), 256, 0, stream>>>(ctx, rsp, embb, Wihb, bih, bhh, xg);
        lstm_persist<<<NB, 512, 0, stream>>>(Whhb, xg, hbuf, bar);
        bilinear<<<BB, 256, 0, stream>>>(hbuf, M, out);   // final h in buffer 0
    } else if (mode == 1) {
        hipMemsetAsync(c_ws, 0, (size_t)ROWS * HH * 4, stream);
        for (int t = 0; t < TT; ++t) {
            const u16* hin = hbuf + (size_t)(t & 1) * ROWS * HH;
            u16* hout      = hbuf + (size_t)((t + 1) & 1) * ROWS * HH;
            step_fused<1><<<256, 256, 0, stream>>>(ctx, rsp, embb, Wihb, Whhb, xg,
                                                   bih, bhh, hin, hout, c_ws, t);
        }
        bilinear<<<BB, 256, 0, stream>>>(hbuf, M, out);
    } else {
        hipMemsetAsync(c_ws, 0, (size_t)ROWS * HH * 4, stream);
        u16* hb = hbuf;
        dim3 sg(G4 / 64, ROWS / 64, 2);
        for (int t = 0; t < TT; ++t) {
            step_gemm_f32<<<sg, 256, 0, stream>>>(ctx, rsp, emb, Wih, Whh, hb, gates, t);
            lstm_update0<<<128, 256, 0, stream>>>(gates, bih, bhh, hb, c_ws);
        }
        bilinear<<<BB, 256, 0, stream>>>(hb, M, out);
    }
}

// Round 5
// 2070.122 us; speedup vs baseline: 7.4091x; 7.4091x over previous
//
#include <hip/hip_runtime.h>
#include <math.h>

// DualEncoder: two LSTMs (B=64,T=160,E=512,H=1024) + bilinear sigmoid.
// mode 2: cvt -> pre_gemm2 (X = emb@Wih^T + bias for all t) -> ONE persistent
//         kernel for 160 recurrent steps: Whh in REGISTERS, h exchanged via
//         sc0/sc1-coherent loads/stores (no threadfence / cache-walk ops),
//         relaxed-atomic grid barrier -> bilinear.
// mode 1/0: fallback paths for smaller workspace (proven in rounds 1-3).

#define BB 64
#define TT 160
#define EE 512
#define HH 1024
#define G4 4096
#define ROWS 128
#define NB 256          // persistent grid size

typedef unsigned short u16;
typedef unsigned int u32;
typedef __attribute__((ext_vector_type(8))) __bf16 bf16x8;
typedef __attribute__((ext_vector_type(8))) short short8;
typedef __attribute__((ext_vector_type(4))) short short4v;
typedef __attribute__((ext_vector_type(4))) float f32x4;

__device__ __forceinline__ u16 f2b(float f) {          // f32 -> bf16 RNE
    unsigned u = __float_as_uint(f);
    u = u + 0x7fffu + ((u >> 16) & 1u);
    return (u16)(u >> 16);
}
__device__ __forceinline__ float b2f(u16 s) { return __uint_as_float(((unsigned)s) << 16); }

__device__ __forceinline__ f32x4 mfma16(short8 a, short8 b, f32x4 c) {
    return __builtin_amdgcn_mfma_f32_16x16x32_bf16(
        __builtin_bit_cast(bf16x8, a), __builtin_bit_cast(bf16x8, b), c, 0, 0, 0);
}

__device__ __forceinline__ void g2l16(const void* gsrc, void* ldst) {
    __builtin_amdgcn_global_load_lds(
        (const __attribute__((address_space(1))) u32*)gsrc,
        (__attribute__((address_space(3))) u32*)ldst, 16, 0, 0);
}

// ---------------- f32 -> bf16 bulk convert ----------------
__global__ __launch_bounds__(256) void cvt_kernel(const float* __restrict__ in,
                                                  u16* __restrict__ out, int n4) {
    int i = blockIdx.x * 256 + threadIdx.x;
    if (i < n4) {
        f32x4 v = *(const f32x4*)(in + (size_t)i * 4);
        short4v o;
        o.x = (short)f2b(v.x); o.y = (short)f2b(v.y);
        o.z = (short)f2b(v.z); o.w = (short)f2b(v.w);
        *(short4v*)(out + (size_t)i * 4) = o;
    }
}

// ---------------- X precompute (verified in round 3) ----------------
__global__ __launch_bounds__(256) void pre_gemm2(
    const int* __restrict__ ctx, const int* __restrict__ rsp,
    const u16* __restrict__ embb, const u16* __restrict__ Wihb,
    const float* __restrict__ bih, const float* __restrict__ bhh,
    u16* __restrict__ xg)
{
    __shared__ __align__(16) u16 As[2][128][64];
    __shared__ __align__(16) u16 Ws[2][128][64];
    __shared__ int toks[128];
    const int tid = threadIdx.x;
    const int n0 = blockIdx.x * 128;
    const int t  = blockIdx.y;

    if (tid < 128) {
        int r = tid;
        toks[tid] = (r < BB) ? ctx[r * TT + t] : rsp[(r - BB) * TT + t];
    }
    __syncthreads();

    const u16* asrc[4]; const u16* bsrc[4];
    #pragma unroll
    for (int q = 0; q < 4; ++q) {
        int i = tid + q * 256;
        int row = i >> 3, c16 = i & 7;
        int scol = ((c16 ^ (row & 7)) * 8);
        asrc[q] = embb + (size_t)toks[row] * EE + scol;
        bsrc[q] = Wihb + (size_t)(n0 + row) * EE + scol;
    }

    const int lane = tid & 63, wave = tid >> 6;
    const int wr = (wave >> 1) * 64, wc = (wave & 1) * 64;
    const int l15 = lane & 15, l4 = lane >> 4;
    f32x4 acc[4][4] = {};

    #pragma unroll
    for (int q = 0; q < 4; ++q) {
        g2l16(asrc[q], (char*)&As[0][0][0] + (tid + q * 256) * 16);
        g2l16(bsrc[q], (char*)&Ws[0][0][0] + (tid + q * 256) * 16);
    }
    for (int it = 0; it < 8; ++it) {
        __syncthreads();
        if (it + 1 < 8) {
            int kk = (it + 1) * 64, bs = (it + 1) & 1;
            #pragma unroll
            for (int q = 0; q < 4; ++q) {
                g2l16(asrc[q] + kk, (char*)&As[bs][0][0] + (tid + q * 256) * 16);
                g2l16(bsrc[q] + kk, (char*)&Ws[bs][0][0] + (tid + q * 256) * 16);
            }
        }
        const int b = it & 1;
        #pragma unroll
        for (int ks = 0; ks < 2; ++ks) {
            int c16 = ks * 4 + l4;
            short8 a[4], w[4];
            #pragma unroll
            for (int mf = 0; mf < 4; ++mf) {
                int R = wr + mf * 16 + l15;
                a[mf] = *(const short8*)((const char*)&As[b][0][0] + R * 128 + ((c16 ^ (R & 7)) << 4));
            }
            #pragma unroll
            for (int nf = 0; nf < 4; ++nf) {
                int Nn = wc + nf * 16 + l15;
                w[nf] = *(const short8*)((const char*)&Ws[b][0][0] + Nn * 128 + ((c16 ^ (Nn & 7)) << 4));
            }
            #pragma unroll
            for (int mf = 0; mf < 4; ++mf)
                #pragma unroll
                for (int nf = 0; nf < 4; ++nf)
                    acc[mf][nf] = mfma16(a[mf], w[nf], acc[mf][nf]);
        }
    }

    u16* xp = xg + (size_t)t * ROWS * G4;
    #pragma unroll
    for (int nf = 0; nf < 4; ++nf) {
        int n = n0 + wc + nf * 16 + l15;
        float bias = bih[n] + bhh[n];
        #pragma unroll
        for (int mf = 0; mf < 4; ++mf)
            #pragma unroll
            for (int q = 0; q < 4; ++q) {
                int r = wr + mf * 16 + l4 * 4 + q;
                xp[(size_t)r * G4 + n] = f2b(acc[mf][nf][q] + bias);
            }
    }
}

// ---------------- persistent recurrent kernel, fence-free ----------------
// 256 blocks x 512 threads (1 block/CU). Block bx: cg=bx&127 (h-cols j0=cg*8),
// rg=bx>>7 (rows r0=rg*64). 8 waves = rsub(2) x kh(4); wave tile 32x32, K=256.
// Whh fragments RESIDENT IN REGISTERS (16 x short8 per lane). h exchanged via
// sc0/sc1 coherent loads/stores (bypass non-coherent per-XCD L2) -- no
// threadfence. K-partials combined in LDS. c in registers (2 cells/thread for
// tid<256). One relaxed-atomic grid barrier per step.
__global__ __launch_bounds__(512) void lstm_persist2(
    const u16* __restrict__ Whhb, const u16* __restrict__ xg,
    u16* __restrict__ hbuf, unsigned* __restrict__ bar)
{
    __shared__ float G[2][2][32][33];                // 16.9 KB

    const int tid = threadIdx.x;
    const int bx = blockIdx.x;
    const int cg = bx & 127, rg = bx >> 7;
    const int r0 = rg * 64, j0 = cg * 8;

    const int lane = tid & 63, wave = tid >> 6;
    const int rsub = wave >> 2;            // 0/1 (row half)
    const int kh   = wave & 3;             // 0..3 (K quarter)
    const int l15 = lane & 15, l4 = lane >> 4;

    // ---- load Whh fragments into registers (once, cached loads) ----
    short8 breg[2][8];
    #pragma unroll
    for (int nf = 0; nf < 2; ++nf) {
        int c = nf * 16 + l15;                     // local output col 0..31
        int n = (c >> 3) * HH + j0 + (c & 7);      // global gate row
        const u16* wp = Whhb + (size_t)n * HH + kh * 256 + l4 * 8;
        #pragma unroll
        for (int ks = 0; ks < 8; ++ks)
            breg[nf][ks] = *(const short8*)(wp + ks * 32);
    }

    // cell ownership: tid<256 own 2 adjacent cells
    const int ur = tid >> 2;               // 0..63 local row
    const int uj = (tid & 3) * 2;          // 0,2,4,6 h-col pair base
    float c0 = 0.f, c1 = 0.f;

    __syncthreads();

    for (int t = 0; t < TT; ++t) {
        const u16* hin = hbuf + (size_t)(t & 1) * ROWS * HH;
        u16* hout      = hbuf + (size_t)((t + 1) & 1) * ROWS * HH;

        // prefetch xg for this step (plain cached loads, consumed after GEMM)
        u32 xv[4] = {0, 0, 0, 0};
        if (tid < 256) {
            const u16* xp = xg + ((size_t)t * ROWS + r0 + ur) * G4 + j0 + uj;
            #pragma unroll
            for (int q = 0; q < 4; ++q) xv[q] = *(const u32*)(xp + q * HH);
        }

        // ---- A loads: coherent (bypass stale L1/L2), all 16 in flight ----
        const u16* abase = hin + (size_t)(r0 + rsub * 32 + l15) * HH + kh * 256 + l4 * 8;
        short8 a[2][8];
        #pragma unroll
        for (int half = 0; half < 2; ++half)
            #pragma unroll
            for (int ks = 0; ks < 8; ++ks)
                asm volatile("global_load_dwordx4 %0, %1, off sc0 sc1"
                             : "=v"(a[half][ks])
                             : "v"(abase + half * 16 * HH + ks * 32));
        asm volatile("s_waitcnt vmcnt(0)" ::: "memory");
        __builtin_amdgcn_sched_barrier(0);

        // ---- MFMAs (B from registers) ----
        f32x4 acc[2][2] = {};
        #pragma unroll
        for (int ks = 0; ks < 8; ++ks) {
            acc[0][0] = mfma16(a[0][ks], breg[0][ks], acc[0][0]);
            acc[0][1] = mfma16(a[0][ks], breg[1][ks], acc[0][1]);
            acc[1][0] = mfma16(a[1][ks], breg[0][ks], acc[1][0]);
            acc[1][1] = mfma16(a[1][ks], breg[1][ks], acc[1][1]);
        }

        // ---- combine K-partials in LDS: kh<2 store, kh>=2 add ----
        if (kh < 2) {
            #pragma unroll
            for (int mf = 0; mf < 2; ++mf)
                #pragma unroll
                for (int nf = 0; nf < 2; ++nf)
                    #pragma unroll
                    for (int q = 0; q < 4; ++q)
                        G[kh][rsub][mf * 16 + l4 * 4 + q][nf * 16 + l15] = acc[mf][nf][q];
        }
        __syncthreads();
        if (kh >= 2) {
            #pragma unroll
            for (int mf = 0; mf < 2; ++mf)
                #pragma unroll
                for (int nf = 0; nf < 2; ++nf)
                    #pragma unroll
                    for (int q = 0; q < 4; ++q)
                        G[kh - 2][rsub][mf * 16 + l4 * 4 + q][nf * 16 + l15] += acc[mf][nf][q];
        }
        __syncthreads();

        // ---- cell update: tid<256, 2 cells each; coherent h store ----
        if (tid < 256) {
            const int rs = ur >> 5, rl = ur & 31;
            float g0[4], g1[4];
            #pragma unroll
            for (int q = 0; q < 4; ++q) {
                float x0 = b2f((u16)(xv[q] & 0xffffu));
                float x1 = b2f((u16)(xv[q] >> 16));
                g0[q] = G[0][rs][rl][q * 8 + uj]     + G[1][rs][rl][q * 8 + uj]     + x0;
                g1[q] = G[0][rs][rl][q * 8 + uj + 1] + G[1][rs][rl][q * 8 + uj + 1] + x1;
            }
            float i0 = 1.f / (1.f + expf(-g0[0])), i1 = 1.f / (1.f + expf(-g1[0]));
            float f0 = 1.f / (1.f + expf(-g0[1])), f1 = 1.f / (1.f + expf(-g1[1]));
            float t0 = tanhf(g0[2]),               t1 = tanhf(g1[2]);
            float o0 = 1.f / (1.f + expf(-g0[3])), o1 = 1.f / (1.f + expf(-g1[3]));
            c0 = f0 * c0 + i0 * t0;
            c1 = f1 * c1 + i1 * t1;
            float h0 = o0 * tanhf(c0), h1 = o1 * tanhf(c1);
            u32 hp = (u32)f2b(h0) | ((u32)f2b(h1) << 16);
            u16* hptr = hout + (size_t)(r0 + ur) * HH + j0 + uj;
            asm volatile("global_store_dword %0, %1, off sc0 sc1"
                         :: "v"(hptr), "v"(hp) : "memory");
        }

        // ---- fence-free grid barrier ----
        if (t < TT - 1) {
            asm volatile("s_waitcnt vmcnt(0)" ::: "memory");  // h stores at coherence point
            __syncthreads();
            if (tid == 0) {
                __hip_atomic_fetch_add(bar, 1u, __ATOMIC_RELAXED, __HIP_MEMORY_SCOPE_AGENT);
                unsigned target = (unsigned)(t + 1) * (unsigned)NB;
                long spins = 0;
                while (__hip_atomic_load(bar, __ATOMIC_RELAXED, __HIP_MEMORY_SCOPE_AGENT) < target) {
                    __builtin_amdgcn_s_sleep(1);
                    if (++spins > 20000000L) break;   // safety bailout
                }
            }
            __syncthreads();
            __builtin_amdgcn_sched_barrier(0);
        }
    }
}

// ---------------- round-3 fallback: fused per-step kernel ----------------
template<int MODE>
__global__ __launch_bounds__(256) void step_fused(
    const int* __restrict__ ctx, const int* __restrict__ rsp,
    const u16* __restrict__ embb, const u16* __restrict__ Wihb,
    const u16* __restrict__ Whhb, const u16* __restrict__ xg,
    const float* __restrict__ bih, const float* __restrict__ bhh,
    const u16* __restrict__ hin, u16* __restrict__ hout,
    float* __restrict__ c_ws, int t)
{
    __shared__ __align__(16) u16 As[2][64][64];
    __shared__ __align__(16) u16 Ws[2][32][64];
    __shared__ float gs[64][32];
    __shared__ int toks[64];

    const int tid = threadIdx.x;
    const int cg = blockIdx.x & 127, rg = blockIdx.x >> 7;
    const int r0 = rg * 64, j0 = cg * 8;

    if (MODE == 1) {
        if (tid < 64) {
            int r = r0 + tid;
            toks[tid] = (r < BB) ? ctx[r * TT + t] : rsp[(r - BB) * TT + t];
        }
        __syncthreads();
    }

    const int arow0 = tid >> 3, c16a = tid & 7;
    const int arow1 = arow0 + 32;
    const int acol0 = ((c16a ^ (arow0 & 7)) * 8);
    const int acol1 = ((c16a ^ (arow1 & 7)) * 8);
    const u16* hA0 = hin + (size_t)(r0 + arow0) * HH + acol0;
    const u16* hA1 = hin + (size_t)(r0 + arow1) * HH + acol1;
    const u16* eA0 = nullptr; const u16* eA1 = nullptr;
    if (MODE == 1) {
        eA0 = embb + (size_t)toks[arow0] * EE + acol0;
        eA1 = embb + (size_t)toks[arow1] * EE + acol1;
    }
    const int nn = tid >> 3, c16b = tid & 7;
    const int bcol = ((c16b ^ (nn & 7)) * 8);
    const int wrow = (nn >> 3) * HH + j0 + (nn & 7);
    const u16* wHh = Whhb + (size_t)wrow * HH + bcol;
    const u16* wIh = (MODE == 1) ? (Wihb + (size_t)wrow * EE + bcol) : nullptr;

    const int NK = (MODE == 1) ? 24 : 16;

    auto stage = [&](int bs, int it) {
        int kk = it * 64;
        const u16 *s0, *s1, *sw;
        if (MODE == 1 && kk < EE) {
            s0 = eA0 + kk; s1 = eA1 + kk; sw = wIh + kk;
        } else {
            int khh = (MODE == 1) ? kk - EE : kk;
            s0 = hA0 + khh; s1 = hA1 + khh; sw = wHh + khh;
        }
        g2l16(s0, (char*)&As[bs][0][0] + tid * 16);
        g2l16(s1, (char*)&As[bs][0][0] + (tid + 256) * 16);
        g2l16(sw, (char*)&Ws[bs][0][0] + tid * 16);
    };

    const int lane = tid & 63, wave = tid >> 6;
    const int wr = wave * 16;
    const int l15 = lane & 15, l4 = lane >> 4;
    f32x4 acc[2] = {};

    stage(0, 0);
    for (int it = 0; it < NK; ++it) {
        __syncthreads();
        if (it + 1 < NK) stage((it + 1) & 1, it + 1);
        const int b = it & 1;
        #pragma unroll
        for (int ks = 0; ks < 2; ++ks) {
            int c16 = ks * 4 + l4;
            int R = wr + l15;
            short8 a = *(const short8*)((const char*)&As[b][0][0] + R * 128 + ((c16 ^ (R & 7)) << 4));
            #pragma unroll
            for (int nf = 0; nf < 2; ++nf) {
                int Nn = nf * 16 + l15;
                short8 w = *(const short8*)((const char*)&Ws[b][0][0] + Nn * 128 + ((c16 ^ (Nn & 7)) << 4));
                acc[nf] = mfma16(a, w, acc[nf]);
            }
        }
    }
    __syncthreads();
    #pragma unroll
    for (int nf = 0; nf < 2; ++nf)
        #pragma unroll
        for (int q = 0; q < 4; ++q)
            gs[wr + l4 * 4 + q][nf * 16 + l15] = acc[nf][q];
    __syncthreads();

    const int e = tid * 2;
    const int row = e >> 3, jj = e & 7;
    const int rglob = r0 + row;
    float g0[4], g1[4];
    #pragma unroll
    for (int g = 0; g < 4; ++g) { g0[g] = gs[row][g * 8 + jj]; g1[g] = gs[row][g * 8 + jj + 1]; }
    if (MODE == 2) {
        const u16* xp = xg + ((size_t)t * ROWS + rglob) * G4 + j0 + jj;
        #pragma unroll
        for (int g = 0; g < 4; ++g) { g0[g] += b2f(xp[g * HH]); g1[g] += b2f(xp[g * HH + 1]); }
    } else {
        #pragma unroll
        for (int g = 0; g < 4; ++g) {
            int n = g * HH + j0 + jj;
            g0[g] += bih[n] + bhh[n];
            g1[g] += bih[n + 1] + bhh[n + 1];
        }
    }
    size_t cidx = ((size_t)blockIdx.x * 64 + row) * 8 + jj;
    float c0 = c_ws[cidx], c1 = c_ws[cidx + 1];
    float i0 = 1.f / (1.f + expf(-g0[0])), i1 = 1.f / (1.f + expf(-g1[0]));
    float f0 = 1.f / (1.f + expf(-g0[1])), f1 = 1.f / (1.f + expf(-g1[1]));
    float t0 = tanhf(g0[2]),               t1 = tanhf(g1[2]);
    float o0 = 1.f / (1.f + expf(-g0[3])), o1 = 1.f / (1.f + expf(-g1[3]));
    float cn0 = f0 * c0 + i0 * t0;
    float cn1 = f1 * c1 + i1 * t1;
    c_ws[cidx] = cn0; c_ws[cidx + 1] = cn1;
    float h0 = o0 * tanhf(cn0), h1 = o1 * tanhf(cn1);
    unsigned hp = (unsigned)f2b(h0) | ((unsigned)f2b(h1) << 16);
    *(unsigned*)(hout + (size_t)rglob * HH + j0 + jj) = hp;
}

// ---------------- mode-0 fallback ----------------
__global__ __launch_bounds__(256) void step_gemm_f32(
    const int* __restrict__ ctx, const int* __restrict__ rsp,
    const float* __restrict__ emb, const float* __restrict__ Wih, const float* __restrict__ Whh,
    const u16* __restrict__ hb, float* __restrict__ gates, int t)
{
    __shared__ __align__(16) u16 As[64][32];
    __shared__ __align__(16) u16 Ws[64][32];
    __shared__ int toks[64];
    const int tid = threadIdx.x;
    const int n0 = blockIdx.x * 64;
    const int r0 = blockIdx.y * 64;
    const int part = blockIdx.z;
    if (tid < 64) {
        int r = r0 + tid;
        toks[tid] = (r < BB) ? ctx[r * TT + t] : rsp[(r - BB) * TT + t];
    }
    __syncthreads();
    const int lane = tid & 63, wave = tid >> 6;
    const int wr = (wave >> 1) * 32, wc = (wave & 1) * 32;
    const int l15 = lane & 15, l4 = lane >> 4;
    f32x4 acc[2][2] = {};
    const int kstart = part * 768;
    const int srow = tid >> 2;
    const int sseg = (tid & 3) * 8;
    for (int it = 0; it < 24; ++it) {
        const int kg = kstart + it * 32;
        const int kk = kg + sseg;
        if (kg < EE) {
            const float* s = emb + (size_t)toks[srow] * EE + kk;
            #pragma unroll
            for (int q = 0; q < 8; ++q) As[srow][sseg + q] = f2b(s[q]);
            const float* sw = Wih + (size_t)(n0 + srow) * EE + kk;
            #pragma unroll
            for (int q = 0; q < 8; ++q) Ws[srow][sseg + q] = f2b(sw[q]);
        } else {
            *(short8*)&As[srow][sseg] = *(const short8*)(hb + (size_t)(r0 + srow) * HH + (kk - EE));
            const float* sw = Whh + (size_t)(n0 + srow) * HH + (kk - EE);
            #pragma unroll
            for (int q = 0; q < 8; ++q) Ws[srow][sseg + q] = f2b(sw[q]);
        }
        __syncthreads();
        #pragma unroll
        for (int mf = 0; mf < 2; ++mf)
            #pragma unroll
            for (int nf = 0; nf < 2; ++nf)
                acc[mf][nf] = mfma16(*(const short8*)&As[wr + mf * 16 + l15][l4 * 8],
                                     *(const short8*)&Ws[wc + nf * 16 + l15][l4 * 8], acc[mf][nf]);
        __syncthreads();
    }
    float* gp = gates + (size_t)part * ROWS * G4;
    #pragma unroll
    for (int mf = 0; mf < 2; ++mf)
        #pragma unroll
        for (int nf = 0; nf < 2; ++nf)
            #pragma unroll
            for (int q = 0; q < 4; ++q) {
                int r = r0 + wr + mf * 16 + l4 * 4 + q;
                int n = n0 + wc + nf * 16 + l15;
                gp[(size_t)r * G4 + n] = acc[mf][nf][q];
            }
}

__global__ __launch_bounds__(256) void lstm_update0(
    const float* __restrict__ gates, const float* __restrict__ bih, const float* __restrict__ bhh,
    u16* __restrict__ hb, float* __restrict__ c)
{
    int idx = blockIdx.x * 256 + threadIdx.x;
    int r = idx >> 8;
    int jj = (idx & 255) * 4;
    const float* gp0 = gates + (size_t)r * G4;
    const float* gp1 = gates + (size_t)(ROWS + r) * G4;
    float gate[4][4];
    #pragma unroll
    for (int g = 0; g < 4; ++g) {
        int n = g * HH + jj;
        f32x4 a = *(const f32x4*)(gp0 + n);
        f32x4 b = *(const f32x4*)(gp1 + n);
        #pragma unroll
        for (int q = 0; q < 4; ++q) gate[g][q] = a[q] + b[q] + bih[n + q] + bhh[n + q];
    }
    int cidx = r * HH + jj;
    f32x4 cv = *(const f32x4*)(c + cidx);
    f32x4 cn; short4v hn;
    #pragma unroll
    for (int q = 0; q < 4; ++q) {
        float si = 1.f / (1.f + expf(-gate[0][q]));
        float sf = 1.f / (1.f + expf(-gate[1][q]));
        float tg = tanhf(gate[2][q]);
        float so = 1.f / (1.f + expf(-gate[3][q]));
        float cval = sf * cv[q] + si * tg;
        cn[q] = cval;
        ((short*)&hn)[q] = (short)f2b(so * tanhf(cval));
    }
    *(f32x4*)(c + cidx) = cn;
    *(short4v*)(hb + cidx) = hn;
}

// ---------------- bilinear head ----------------
__global__ __launch_bounds__(256) void bilinear(
    const u16* __restrict__ hb, const float* __restrict__ M, float* __restrict__ out)
{
    int b = blockIdx.x;
    __shared__ float chs[HH];
    __shared__ float red[256];
    const u16* ch = hb + (size_t)b * HH;
    const u16* rh = hb + (size_t)(BB + b) * HH;
    for (int i = threadIdx.x; i < HH; i += 256) chs[i] = b2f(ch[i]);
    __syncthreads();
    float vj[4] = {0.f, 0.f, 0.f, 0.f};
    for (int i = 0; i < HH; ++i) {
        float chi = chs[i];
        const float* Mr = M + (size_t)i * HH;
        #pragma unroll
        for (int q = 0; q < 4; ++q) vj[q] += chi * Mr[threadIdx.x + q * 256];
    }
    float acc = 0.f;
    #pragma unroll
    for (int q = 0; q < 4; ++q) acc += vj[q] * b2f(rh[threadIdx.x + q * 256]);
    red[threadIdx.x] = acc;
    __syncthreads();
    for (int s = 128; s > 0; s >>= 1) {
        if (threadIdx.x < s) red[threadIdx.x] += red[threadIdx.x + s];
        __syncthreads();
    }
    if (threadIdx.x == 0) out[b] = 1.0f / (1.0f + expf(-red[0]));
}

extern "C" void kernel_launch(void* const* d_in, const int* in_sizes, int n_in,
                              void* d_out, int out_size, void* d_ws, size_t ws_size,
                              hipStream_t stream) {
    const int*   ctx = (const int*)d_in[0];
    const int*   rsp = (const int*)d_in[1];
    const float* emb = (const float*)d_in[2];
    const float* Wih = (const float*)d_in[3];
    const float* Whh = (const float*)d_in[4];
    const float* bih = (const float*)d_in[5];
    const float* bhh = (const float*)d_in[6];
    const float* M   = (const float*)d_in[7];
    float* out = (float*)d_out;

    // workspace layout
    char* w = (char*)d_ws;
    u16*   hbuf  = (u16*)w;   w += (size_t)2 * ROWS * HH * 2;      // 512 KB
    float* c_ws  = (float*)w; w += (size_t)ROWS * HH * 4;          // 512 KB
    float* gates = (float*)w; w += (size_t)2 * ROWS * G4 * 4;      // 4 MB (mode 0)
    u16*   embb  = (u16*)w;   w += (size_t)32000 * EE * 2;         // 31.25 MB
    u16*   Wihb  = (u16*)w;   w += (size_t)G4 * EE * 2;            // 4 MB
    u16*   Whhb  = (u16*)w;   w += (size_t)G4 * HH * 2;            // 8 MB
    unsigned* bar = (unsigned*)w; w += 256;                        // barrier
    size_t conv_need = (size_t)(w - (char*)d_ws);
    u16*   xg    = (u16*)w;   w += (size_t)TT * ROWS * G4 * 2;     // 160 MB
    size_t xpre_need = (size_t)(w - (char*)d_ws);

    int mode = (ws_size >= xpre_need) ? 2 : (ws_size >= conv_need) ? 1 : 0;

    hipMemsetAsync(hbuf, 0, (size_t)2 * ROWS * HH * 2, stream);

    if (mode >= 1) {
        cvt_kernel<<<16000, 256, 0, stream>>>(emb, embb, 32000 * EE / 4);
        cvt_kernel<<<2048,  256, 0, stream>>>(Wih, Wihb, G4 * EE / 4);
        cvt_kernel<<<4096,  256, 0, stream>>>(Whh, Whhb, G4 * HH / 4);
    }

    if (mode == 2) {
        hipMemsetAsync(bar, 0, 256, stream);
        pre_gemm2<<<dim3(G4 / 128, TT), 256, 0, stream>>>(ctx, rsp, embb, Wihb, bih, bhh, xg);
        lstm_persist2<<<NB, 512, 0, stream>>>(Whhb, xg, hbuf, bar);
        bilinear<<<BB, 256, 0, stream>>>(hbuf, M, out);   // final h in buffer 0
    } else if (mode == 1) {
        hipMemsetAsync(c_ws, 0, (size_t)ROWS * HH * 4, stream);
        for (int t = 0; t < TT; ++t) {
            const u16* hin = hbuf + (size_t)(t & 1) * ROWS * HH;
            u16* hout      = hbuf + (size_t)((t + 1) & 1) * ROWS * HH;
            step_fused<1><<<256, 256, 0, stream>>>(ctx, rsp, embb, Wihb, Whhb, xg,
                                                   bih, bhh, hin, hout, c_ws, t);
        }
        bilinear<<<BB, 256, 0, stream>>>(hbuf, M, out);
    } else {
        hipMemsetAsync(c_ws, 0, (size_t)ROWS * HH * 4, stream);
        u16* hb = hbuf;
        dim3 sg(G4 / 64, ROWS / 64, 2);
        for (int t = 0; t < TT; ++t) {
            step_gemm_f32<<<sg, 256, 0, stream>>>(ctx, rsp, emb, Wih, Whh, hb, gates, t);
            lstm_update0<<<128, 256, 0, stream>>>(gates, bih, bhh, hb, c_ws);
        }
        bilinear<<<BB, 256, 0, stream>>>(hb, M, out);
    }
}